// Round 2
// baseline (8120.412 us; speedup 1.0000x reference)
//
#include <hip/hip_runtime.h>

#define TT 1024
#define DU 256

// workspace layout (bytes)
#define CEX_OFF   0          // bf16 c slots: [8 grp][16 mem][16 b][16 c] (65536 B)
#define HEX_OFF   65536      // bf16 h slots: same layout (65536 B)
#define STMP_OFF  131072     // u32 stamps: [8 grp][16 mem] (512 B)
#define TST_OFF   131584     // self-test region: 8 grp x 1024 B (8192 B)
#define BLOB_OFF  139776     // 16 member chunks of bf16 weights
#define CHUNK_ELEMS (11*16*256)   // per-member: 11 mats x 16 cols x 256 k

typedef unsigned short ushort_t;
typedef unsigned u32;
typedef unsigned long long u64;
typedef __attribute__((ext_vector_type(8))) short short8;
typedef __attribute__((ext_vector_type(4))) float floatx4;

#define MFMA(a, b, c) __builtin_amdgcn_mfma_f32_16x16x32_bf16((a), (b), (c), 0, 0, 0)

__device__ __forceinline__ ushort_t f2bf(float f) {
  unsigned u = __float_as_uint(f);
  return (ushort_t)((u + 0x7fffu + ((u >> 16) & 1u)) >> 16);
}
__device__ __forceinline__ float sigf(float x) { return 1.0f / (1.0f + __expf(-x)); }
__device__ __forceinline__ float tanhf_(float x) {
  float t = 1.0f - 2.0f / (__expf(2.0f * fabsf(x)) + 1.0f);
  return copysignf(t, x);
}

// ---------------- slow (agent/MALL) exchange: proven, byte-identical to baseline ----------------
__device__ __forceinline__ short8 ldfrag(const ushort_t* p) {
  union { struct { u64 a, b; } q; short8 s; } v;
  v.q.a = __hip_atomic_load((const u64*)p,       __ATOMIC_RELAXED, __HIP_MEMORY_SCOPE_AGENT);
  v.q.b = __hip_atomic_load((const u64*)(p + 4), __ATOMIC_RELAXED, __HIP_MEMORY_SCOPE_AGENT);
  return v.s;
}
__device__ __forceinline__ void wait_st(const u32* st, u32 tgt, int lane) {
  for (;;) {
    u32 s = __hip_atomic_load(st + (lane & 15), __ATOMIC_RELAXED, __HIP_MEMORY_SCOPE_AGENT);
    if (__all((int)(s >= tgt))) return;
    __builtin_amdgcn_s_sleep(1);
  }
}

// ---------------- fast (intra-XCD, shared-L2) exchange — ONLY used after the
// runtime self-test below has verified, on this silicon and this dispatch, that
// plain stores -> vmcnt(0) -> sc0 loads round-trip through the shared L2. ----
__device__ __forceinline__ u32 ld_stamp_sc0(const u32* p) {
  u32 s;
  asm volatile("global_load_dword %0, %1, off sc0\n\ts_waitcnt vmcnt(0)"
               : "=v"(s) : "v"(p) : "memory");
  return s;
}
// capped poll: returns 1 on success, 0 on wedge (caller sets sticky flag)
__device__ __forceinline__ int wait_st_fast(const u32* st, u32 tgt, int lane) {
  const u32* p = st + (lane & 15);
  int it = 0;
  for (;;) {
    u32 s = ld_stamp_sc0(p);
    if (__all((int)(s >= tgt))) return 1;
    if (++it > 16384) return 0;              // ~2 ms: terminate instead of hang
    __builtin_amdgcn_s_sleep(1);
  }
}
// issue-only 16B sc0 load; caller does ONE vmcnt(0) + sched_barrier(0) after batch
__device__ __forceinline__ short8 ldfrag_sc0_issue(const ushort_t* p) {
  short8 v;
  asm volatile("global_load_dwordx4 %0, %1, off sc0" : "=v"(v) : "v"(p));
  return v;
}
__device__ __forceinline__ void pub_fast(ushort_t* dp, u64 v, u32* sp, u32 sv, int leader) {
  asm volatile("global_store_dwordx2 %0, %1, off" :: "v"(dp), "v"(v) : "memory");
  asm volatile("s_waitcnt vmcnt(0)" ::: "memory");   // data at L2 before stamp
  if (leader)
    asm volatile("global_store_dword %0, %1, off" :: "v"(sp), "v"(sv) : "memory");
}

// ---- weight conversion: blob[mem][mat][col][k] bf16, k contiguous ----
__global__ void conv_weights(
    const float* __restrict__ wf, const float* __restrict__ wi,
    const float* __restrict__ wc, const float* __restrict__ wo,
    const float* __restrict__ rf, const float* __restrict__ ri,
    const float* __restrict__ rc, const float* __restrict__ ro,
    const float* __restrict__ pf, const float* __restrict__ pi,
    const float* __restrict__ po, ushort_t* __restrict__ blob)
{
  int id = blockIdx.x * 256 + threadIdx.x;   // 720896 total, exact
  int k   = id & 255;
  int col = (id >> 8) & 15;
  int q   = id >> 12;          // 0..175
  int m   = q % 11;
  int mm  = q / 11;
  const float* srcs[11] = {wf, wi, wc, wo, rf, ri, rc, ro, pf, pi, po};
  float v = srcs[m][k * 256 + mm * 16 + col];
  unsigned u = __float_as_uint(v);
  blob[id] = (ushort_t)((u + 0x7fffu + ((u >> 16) & 1u)) >> 16);
}

// ---- persistent recurrent kernel ----
extern "C" __global__ void __launch_bounds__(128, 1)
lstm_rec(const float* __restrict__ x, const ushort_t* __restrict__ blob,
         ushort_t* __restrict__ h_ex, ushort_t* __restrict__ c_ex,
         u32* __restrict__ stamps, u32* __restrict__ tst,
         const float* __restrict__ bfv, const float* __restrict__ biv,
         const float* __restrict__ bcv, const float* __restrict__ bov,
         float* __restrict__ out)
{
  __shared__ ushort_t xa[16 * 264];     // x(t) bf16, row stride 264
  __shared__ float pre[4][16][17];      // gate preacts
  __shared__ float pop[16][17];         // po partial (wave1)
  __shared__ float cn_f32[16][16];      // own-col c state, f32
  __shared__ ushort_t cn_bf[16][16];
  __shared__ ushort_t hn_bf[16][16];
  __shared__ float bia[4][16];
  __shared__ int s_fast;

  const int tid = threadIdx.x;
  const int bid = blockIdx.x;
  const int grp = bid & 7;
  const int mem = bid >> 3;
  const int gb0 = grp * 16;
  const int gc0 = mem * 16;

  const int wv = tid >> 6;
  const int lane = tid & 63;
  const int lr = lane & 15;
  const int lk = lane >> 4;

  // ---- weight fragments -> registers ----
  const ushort_t* wb = blob + (size_t)mem * CHUNK_ELEMS;
  short8 wXa[8], wXb[8], wRa[8], wRb[8], wPa[8], wPb[8];
  {
    const int m0 = wv ? 2 : 0;
    const int p0 = wv ? 10 : 8;
    const int p1 = wv ? 10 : 9;
#pragma unroll
    for (int s = 0; s < 8; ++s) {
      const int ko = s * 32 + lk * 8;
      wXa[s] = *(const short8*)(wb + ((m0    ) * 16 + lr) * 256 + ko);
      wXb[s] = *(const short8*)(wb + ((m0 + 1) * 16 + lr) * 256 + ko);
      wRa[s] = *(const short8*)(wb + ((m0 + 4) * 16 + lr) * 256 + ko);
      wRb[s] = *(const short8*)(wb + ((m0 + 5) * 16 + lr) * 256 + ko);
      wPa[s] = *(const short8*)(wb + (p0 * 16 + lr) * 256 + ko);
      wPb[s] = *(const short8*)(wb + (p1 * 16 + lr) * 256 + ko);
    }
  }

  if (tid < 64) {
    const float* bs = (tid < 16) ? bfv : (tid < 32) ? biv : (tid < 48) ? bcv : bov;
    bia[tid >> 4][tid & 15] = bs[gc0 + (tid & 15)];
  }
  const int pb = tid >> 3, pc = (tid & 7) * 2;
  cn_f32[pb][pc] = 0.f;
  cn_f32[pb][pc + 1] = 0.f;

  // stage x(0) -> xa (bf16)
  const int xr = tid >> 3, xc = (tid & 7) * 32;
  {
    const float* xp = x + (size_t)(gb0 + xr) * TT * DU + xc;
#pragma unroll
    for (int u = 0; u < 8; ++u) {
      float4 f = *(const float4*)(xp + u * 4);
      u64 pk = (u64)f2bf(f.x) | ((u64)f2bf(f.y) << 16) |
               ((u64)f2bf(f.z) << 32) | ((u64)f2bf(f.w) << 48);
      *(u64*)&xa[xr * 264 + xc + u * 4] = pk;
    }
  }

  // ======== runtime self-test: is the intra-group L2 (sc0) pipe functional? ========
  // Layout per group (1024 B, all control words on DISTINCT 64B lines from any
  // plain-store target to avoid dirty-L2-line vs MALL-word clobber):
  //   u64 tdata[64]   bytes   0..511  (plain-store target, lines 0-7)
  //   u32 tready[16]  bytes 512..575  (agent only, line 8)
  //   u32 tverd[16]   bytes 576..639  (agent only, line 9)
  //   u32 tstamp      byte  640       (plain-store target, line 10)
  //   u32 tdec        byte  704       (agent only, line 11)
  if (wv == 0) {
    u32* tb     = tst + grp * 256;
    u64* tdata  = (u64*)tb;
    u32* tready = tb + 128;
    u32* tverd  = tb + 144;
    u32* tstamp = tb + 160;
    u32* tdec   = tb + 176;
    int ok = 1;

    // pollute this CU's L1 with the current (about-to-be-stale) copies
    {
      u64 pd; u32 ps;
      asm volatile("global_load_dwordx2 %0, %2, off\n\t"
                   "global_load_dword %1, %3, off\n\t"
                   "s_waitcnt vmcnt(0)"
                   : "=v"(pd), "=v"(ps)
                   : "v"(tdata + lane), "v"(tstamp) : "memory");
      asm volatile("" :: "v"(pd), "v"(ps));   // keep live
    }

    for (int round = 1; round <= 2; ++round) {
      u64 expect = (0x9E3779B97F4A7C15ull * (u64)round) ^
                   ((u64)lane << 56) ^ (u64)(lane * 0x01010101u);
      if (lane == 0)
        __hip_atomic_store(tready + mem, (u32)round, __ATOMIC_RELEASE, __HIP_MEMORY_SCOPE_AGENT);
      if (mem == 0) {
        int it = 0;
        for (;;) {   // wait all members ready (agent, capped)
          u32 r = (lane < 16)
            ? __hip_atomic_load(tready + lane, __ATOMIC_RELAXED, __HIP_MEMORY_SCOPE_AGENT)
            : 0xFFFFFFFFu;
          if (__all((int)(r >= (u32)round))) break;
          if (++it > 4096) { ok = 0; break; }
          __builtin_amdgcn_s_sleep(2);
        }
        // publish pattern with the EXACT steady-state sequence
        asm volatile("global_store_dwordx2 %0, %1, off" :: "v"(tdata + lane), "v"(expect) : "memory");
        asm volatile("s_waitcnt vmcnt(0)" ::: "memory");
        if (lane == 0) {
          u32 sv = 0x5AA5F000u + (u32)round;
          asm volatile("global_store_dword %0, %1, off" :: "v"(tstamp), "v"(sv) : "memory");
        }
      }
      // all members: sc0-poll the stamp (capped), then sc0-read + verify data
      int saw = 0;
      {
        int it = 0;
        u32 want = 0x5AA5F000u + (u32)round;
        for (;;) {
          u32 s = ld_stamp_sc0(tstamp);
          if (__all((int)(s == want))) { saw = 1; break; }
          if (++it > 4096) break;
          __builtin_amdgcn_s_sleep(2);
        }
      }
      if (saw) {
        u64 v;
        asm volatile("global_load_dwordx2 %0, %1, off sc0\n\ts_waitcnt vmcnt(0)"
                     : "=v"(v) : "v"(tdata + lane) : "memory");
        if (!__all((int)(v == expect))) ok = 0;
      } else ok = 0;
    }
    if (lane == 0)
      __hip_atomic_store(tverd + mem, ok ? 2u : 1u, __ATOMIC_RELEASE, __HIP_MEMORY_SCOPE_AGENT);
    // single decider (member 0) -> consistent group-wide verdict
    if (mem == 0) {
      u32 dec = 2; int it = 0;
      for (;;) {
        u32 vv = (lane < 16)
          ? __hip_atomic_load(tverd + lane, __ATOMIC_RELAXED, __HIP_MEMORY_SCOPE_AGENT) : 2u;
        if (__all((int)(vv != 0u))) { if (!__all((int)(vv == 2u))) dec = 1; break; }
        if (++it > 8192) { dec = 1; break; }
        __builtin_amdgcn_s_sleep(2);
      }
      if (lane == 0)
        __hip_atomic_store(tdec, dec, __ATOMIC_RELEASE, __HIP_MEMORY_SCOPE_AGENT);
    }
    // wait decision on the proven agent path (member 0 always publishes)
    u32 d;
    for (;;) {
      d = __hip_atomic_load(tdec, __ATOMIC_RELAXED, __HIP_MEMORY_SCOPE_AGENT);
      if (d) break;
      __builtin_amdgcn_s_sleep(2);
    }
    if (lane == 0) s_fast = (d == 2u);
  }
  __syncthreads();                         // xa ready + s_fast ready
  const bool fast = (s_fast != 0);
  int wedged = 0;                          // sticky: capped fast-wait failed

  const floatx4 z4 = {0.f, 0.f, 0.f, 0.f};
  floatx4 accA = z4, accB = z4;
  // prologue: x(0)@W  (c(-1)=0 so no peephole term)
#pragma unroll
  for (int s = 0; s < 8; ++s) {
    short8 a = *(const short8*)&xa[lr * 264 + s * 32 + lk * 8];
    accA = MFMA(a, wXa[s], accA);
    accB = MFMA(a, wXb[s], accB);
  }

  u32* stG = stamps + grp * 16;
  ushort_t* cG = c_ex + grp * 16 * 256;   // 16 slots x 256 ushorts (512 B)
  ushort_t* hG = h_ex + grp * 16 * 256;
  const int sb = lane >> 2, sc = (lane & 3) * 4;

  for (int t = 0; t < TT; ++t) {
    // ---- h-part: wait h(t-1), pre += h(t-1)@R ----
    if (t > 0) {
      if (fast) {
        if (!wedged && !wait_st_fast(stG, 2u * (u32)t, lane)) wedged = 1;
        short8 hf[8];
#pragma unroll
        for (int s = 0; s < 8; ++s) {
          int k = s * 32 + lk * 8;
          hf[s] = ldfrag_sc0_issue(hG + (k >> 4) * 256 + lr * 16 + (k & 15));
        }
        asm volatile("s_waitcnt vmcnt(0)" ::: "memory");
        __builtin_amdgcn_sched_barrier(0);
#pragma unroll
        for (int s = 0; s < 8; ++s) {
          accA = MFMA(hf[s], wRa[s], accA);
          accB = MFMA(hf[s], wRb[s], accB);
        }
      } else {
        wait_st(stG, 2u * (u32)t, lane);
#pragma unroll
        for (int s = 0; s < 8; ++s) {
          int k = s * 32 + lk * 8;
          short8 hf = ldfrag(hG + (k >> 4) * 256 + lr * 16 + (k & 15));
          accA = MFMA(hf, wRa[s], accA);
          accB = MFMA(hf, wRb[s], accB);
        }
      }
    }
#pragma unroll
    for (int r = 0; r < 4; ++r) {
      pre[wv * 2    ][lk * 4 + r][lr] = accA[r];
      pre[wv * 2 + 1][lk * 4 + r][lr] = accB[r];
    }
    __syncthreads();                                  // S1: pre complete

    // ---- pointwise 1: f,i,c~ -> c_new ----
#pragma unroll
    for (int e = 0; e < 2; ++e) {
      int c = pc + e;
      float fg = sigf(pre[0][pb][c] + bia[0][c]);
      float ig = sigf(pre[1][pb][c] + bia[1][c]);
      float ct = tanhf_(pre[2][pb][c] + bia[2][c]);
      float cn = fg * cn_f32[pb][c] + ig * ct;
      cn_f32[pb][c] = cn;
      cn_bf[pb][c] = f2bf(cn);
    }
    __syncthreads();                                  // S2: cn_bf complete

    // ---- publish c ----
    if (wv == 0) {
      u64 v = *(const u64*)&cn_bf[sb][sc];
      if (fast) {
        pub_fast(cG + mem * 256 + sb * 16 + sc, v, stG + mem, 2u * (u32)t + 1u, lane == 0);
      } else {
        __hip_atomic_store((u64*)(cG + mem * 256 + sb * 16 + sc), v,
                           __ATOMIC_RELAXED, __HIP_MEMORY_SCOPE_AGENT);
        asm volatile("s_waitcnt vmcnt(0)" ::: "memory");
        if (lane == 0)
          __hip_atomic_store(stG + mem, 2u * (u32)t + 1u,
                             __ATOMIC_RELAXED, __HIP_MEMORY_SCOPE_AGENT);
      }
    }

    // ---- x(t+1) HBM prefetch fills the c-wait window ----
    float4 xf[8];
    if (t < TT - 1) {
      const float* xp = x + ((size_t)(gb0 + xr) * TT + (t + 1)) * DU + xc;
#pragma unroll
      for (int u = 0; u < 8; ++u) xf[u] = *(const float4*)(xp + u * 4);
    }
    if (fast) { if (!wedged && !wait_st_fast(stG, 2u * (u32)t + 1u, lane)) wedged = 1; }
    else      wait_st(stG, 2u * (u32)t + 1u, lane);   // c(t) visible

    // ---- phase B: po matvec (wave1) + next-step peepholes (wave0) ----
    {
      short8 cf[8];
      if (fast) {
#pragma unroll
        for (int s = 0; s < 8; ++s) {
          int k = s * 32 + lk * 8;
          cf[s] = ldfrag_sc0_issue(cG + (k >> 4) * 256 + lr * 16 + (k & 15));
        }
        asm volatile("s_waitcnt vmcnt(0)" ::: "memory");
        __builtin_amdgcn_sched_barrier(0);
      } else {
#pragma unroll
        for (int s = 0; s < 8; ++s) {
          int k = s * 32 + lk * 8;
          cf[s] = ldfrag(cG + (k >> 4) * 256 + lr * 16 + (k & 15));
        }
      }
      if (wv == 0) {
        accA = z4; accB = z4;                          // start step-t+1 accumulators
#pragma unroll
        for (int s = 0; s < 8; ++s) {
          accA = MFMA(cf[s], wPa[s], accA);            // c(t)@pf
          accB = MFMA(cf[s], wPb[s], accB);            // c(t)@pi
        }
      } else {
        floatx4 pacc = z4;
#pragma unroll
        for (int s = 0; s < 8; ++s)
          pacc = MFMA(cf[s], wPa[s], pacc);            // c(t)@po
#pragma unroll
        for (int r = 0; r < 4; ++r) pop[lk * 4 + r][lr] = pacc[r];
      }
    }
    __syncthreads();                                  // S5: pop complete

    // ---- pointwise 2: o gate, h_new ----
#pragma unroll
    for (int e = 0; e < 2; ++e) {
      int c = pc + e;
      float og = sigf(pre[3][pb][c] + pop[pb][c] + bia[3][c]);
      float hv = tanhf_(cn_f32[pb][c]) * og;
      hn_bf[pb][c] = f2bf(hv);
      if (t == TT - 1) out[(gb0 + pb) * 256 + gc0 + c] = hv;
    }
    if (t == TT - 1) break;
    __syncthreads();                                  // S6: hn_bf complete

    // ---- publish h ----
    if (wv == 0) {
      u64 v = *(const u64*)&hn_bf[sb][sc];
      if (fast) {
        pub_fast(hG + mem * 256 + sb * 16 + sc, v, stG + mem, 2u * (u32)t + 2u, lane == 0);
      } else {
        __hip_atomic_store((u64*)(hG + mem * 256 + sb * 16 + sc), v,
                           __ATOMIC_RELAXED, __HIP_MEMORY_SCOPE_AGENT);
        asm volatile("s_waitcnt vmcnt(0)" ::: "memory");
        if (lane == 0)
          __hip_atomic_store(stG + mem, 2u * (u32)t + 2u,
                             __ATOMIC_RELAXED, __HIP_MEMORY_SCOPE_AGENT);
      }
    }

    // ---- stage x(t+1) into LDS, then x@W fills the h-wait window ----
#pragma unroll
    for (int u = 0; u < 8; ++u) {
      float4 f = xf[u];
      u64 pk = (u64)f2bf(f.x) | ((u64)f2bf(f.y) << 16) |
               ((u64)f2bf(f.z) << 32) | ((u64)f2bf(f.w) << 48);
      *(u64*)&xa[xr * 264 + xc + u * 4] = pk;
    }
    __syncthreads();                                  // S8: xa ready

    if (wv == 1) { accA = z4; accB = z4; }            // c~,o restart
#pragma unroll
    for (int s = 0; s < 8; ++s) {
      short8 a = *(const short8*)&xa[lr * 264 + s * 32 + lk * 8];
      accA = MFMA(a, wXa[s], accA);
      accB = MFMA(a, wXb[s], accB);
    }
    // loop head waits h-stamps (2t+2) before using h frags
  }
}

extern "C" void kernel_launch(void* const* d_in, const int* in_sizes, int n_in,
                              void* d_out, int out_size, void* d_ws, size_t ws_size,
                              hipStream_t stream) {
  const float* x   = (const float*)d_in[0];
  const float* bfv = (const float*)d_in[12];
  const float* biv = (const float*)d_in[13];
  const float* bcv = (const float*)d_in[14];
  const float* bov = (const float*)d_in[15];
  float* outp = (float*)d_out;

  char* ws = (char*)d_ws;
  ushort_t* c_exp = (ushort_t*)(ws + CEX_OFF);
  ushort_t* h_exp = (ushort_t*)(ws + HEX_OFF);
  u32* stmp = (u32*)(ws + STMP_OFF);
  u32* tstp = (u32*)(ws + TST_OFF);
  ushort_t* blob = (ushort_t*)(ws + BLOB_OFF);

  // zero exchange buffers + stamps + test region (must restart at 0 every replay)
  hipMemsetAsync(d_ws, 0, BLOB_OFF, stream);

  hipLaunchKernelGGL(conv_weights, dim3(2816), dim3(256), 0, stream,
                     (const float*)d_in[1], (const float*)d_in[2],
                     (const float*)d_in[3], (const float*)d_in[4],
                     (const float*)d_in[5], (const float*)d_in[6],
                     (const float*)d_in[7], (const float*)d_in[8],
                     (const float*)d_in[9], (const float*)d_in[10],
                     (const float*)d_in[11], blob);

  hipLaunchKernelGGL(lstm_rec, dim3(128), dim3(128), 0, stream,
                     x, (const ushort_t*)blob, h_exp, c_exp, stmp, tstp,
                     bfv, biv, bcv, bov, outp);
}

// Round 3
// 7043.950 us; speedup vs baseline: 1.1528x; 1.1528x over previous
//
#include <hip/hip_runtime.h>

#define TT 1024
#define DU 256

// workspace layout (bytes)
#define CEX_OFF   0          // bf16 c slots: [8 grp][16 mem][16 b][16 c] (65536 B)
#define HEX_OFF   65536      // bf16 h slots: same layout (65536 B)
#define STMP_OFF  131072     // u32 stamps: [8 grp][16 mem][16 pad] — 64B line per member (8192 B)
#define TST_OFF   139264     // self-test region: 8 grp x 4096 B (32768 B)
#define BLOB_OFF  172032     // 16 member chunks of bf16 weights
#define CHUNK_ELEMS (11*16*256)   // per-member: 11 mats x 16 cols x 256 k

typedef unsigned short ushort_t;
typedef unsigned u32;
typedef unsigned long long u64;
typedef __attribute__((ext_vector_type(8))) short short8;
typedef __attribute__((ext_vector_type(4))) float floatx4;

#define MFMA(a, b, c) __builtin_amdgcn_mfma_f32_16x16x32_bf16((a), (b), (c), 0, 0, 0)

__device__ __forceinline__ ushort_t f2bf(float f) {
  unsigned u = __float_as_uint(f);
  return (ushort_t)((u + 0x7fffu + ((u >> 16) & 1u)) >> 16);
}
__device__ __forceinline__ float sigf(float x) { return 1.0f / (1.0f + __expf(-x)); }
__device__ __forceinline__ float tanhf_(float x) {
  float t = 1.0f - 2.0f / (__expf(2.0f * fabsf(x)) + 1.0f);
  return copysignf(t, x);
}

// ---- flavored primitives ----
// sc0 = L2(XCD)-scoped; sc1 = device-scoped (proven by baseline).
__device__ __forceinline__ void st_u64_flav(u64* p, u64 v, int sc0flav) {
  if (sc0flav)
    asm volatile("global_store_dwordx2 %0, %1, off sc0" :: "v"(p), "v"(v) : "memory");
  else
    asm volatile("global_store_dwordx2 %0, %1, off sc1" :: "v"(p), "v"(v) : "memory");
}
__device__ __forceinline__ void st_u32_flav(u32* p, u32 v, int sc0flav) {
  if (sc0flav)
    asm volatile("global_store_dword %0, %1, off sc0" :: "v"(p), "v"(v) : "memory");
  else
    asm volatile("global_store_dword %0, %1, off sc1" :: "v"(p), "v"(v) : "memory");
}
__device__ __forceinline__ u32 ld_u32_sc0(const u32* p) {
  u32 s;
  asm volatile("global_load_dword %0, %1, off sc0\n\ts_waitcnt vmcnt(0)"
               : "=v"(s) : "v"(p) : "memory");
  return s;
}
// agent-scope (slow, proven) fragment load
__device__ __forceinline__ short8 ldfrag(const ushort_t* p) {
  union { struct { u64 a, b; } q; short8 s; } v;
  v.q.a = __hip_atomic_load((const u64*)p,       __ATOMIC_RELAXED, __HIP_MEMORY_SCOPE_AGENT);
  v.q.b = __hip_atomic_load((const u64*)(p + 4), __ATOMIC_RELAXED, __HIP_MEMORY_SCOPE_AGENT);
  return v.s;
}
// issue-only 16B sc0 load; caller does ONE vmcnt(0) + sched_barrier(0) after batch
__device__ __forceinline__ short8 ldfrag_sc0_issue(const ushort_t* p) {
  short8 v;
  asm volatile("global_load_dwordx4 %0, %1, off sc0" : "=v"(v) : "v"(p));
  return v;
}

// stamps: one 64B line per member; member m's word at stG + m*16.
// returns 1 ok, 0 wedge (mode>0 only; mode 0 never wedges — baseline-proven)
__device__ __forceinline__ int wait_stamps(const u32* stG, u32 tgt, int lane, int mode) {
  const u32* p = stG + (lane & 15) * 16;
  if (mode) {
    int it = 0;
    for (;;) {
      u32 s = ld_u32_sc0(p);
      if (__all((int)(s >= tgt))) return 1;
      if (++it > 16384) return 0;
      __builtin_amdgcn_s_sleep(1);
    }
  } else {
    for (;;) {
      u32 s = __hip_atomic_load(p, __ATOMIC_RELAXED, __HIP_MEMORY_SCOPE_AGENT);
      if (__all((int)(s >= tgt))) return 1;
      __builtin_amdgcn_s_sleep(1);
    }
  }
}
// publish: data store -> vmcnt(0) -> stamp store, in the mode's flavor
__device__ __forceinline__ void publish(ushort_t* dp, u64 v, u32* sp, u32 sv,
                                        int leader, int mode) {
  if (mode == 2) {
    asm volatile("global_store_dwordx2 %0, %1, off sc0" :: "v"(dp), "v"(v) : "memory");
    asm volatile("s_waitcnt vmcnt(0)" ::: "memory");
    if (leader)
      asm volatile("global_store_dword %0, %1, off sc0" :: "v"(sp), "v"(sv) : "memory");
  } else if (mode == 1) {
    asm volatile("global_store_dwordx2 %0, %1, off sc1" :: "v"(dp), "v"(v) : "memory");
    asm volatile("s_waitcnt vmcnt(0)" ::: "memory");
    if (leader)
      asm volatile("global_store_dword %0, %1, off sc1" :: "v"(sp), "v"(sv) : "memory");
  } else {
    __hip_atomic_store((u64*)dp, v, __ATOMIC_RELAXED, __HIP_MEMORY_SCOPE_AGENT);
    asm volatile("s_waitcnt vmcnt(0)" ::: "memory");
    if (leader)
      __hip_atomic_store(sp, sv, __ATOMIC_RELAXED, __HIP_MEMORY_SCOPE_AGENT);
  }
}

// ---- per-group protocol self-test (wv0 only). All 16 members publish with the
// candidate store flavor; all verify all via sc0 loads after L1/L2 pollution.
// Test layout per group (u32 offsets in tb): tdata u64[128] @0, tstamp lines
// @256 (+m*16), tready @512, tverdA @528, tdecA @544, tverdB @560, tdecB @576.
__device__ int test_combo(u32* tb, int mem, int lane, int sc0flav, u32 seqbase) {
  u64* td = (u64*)tb;
  u32* tstamp = tb + 256;
  u32* tready = tb + 512;
  int ok = 1;
  for (int r = 0; r < 2; ++r) {
    u32 seq = seqbase + r;
    // pollute consumer L1 (and shared L2) with the stale copies
    {
      u64 a = td[lane];
      u64 b = td[lane + 64];
      u32 s = tstamp[(lane & 15) * 16];
      asm volatile("" :: "v"(a), "v"(b), "v"(s));
    }
    // round-entry handshake on the proven agent path (serializes rounds)
    if (lane == 0)
      __hip_atomic_store(tready + mem, seq, __ATOMIC_RELEASE, __HIP_MEMORY_SCOPE_AGENT);
    {
      int it = 0;
      for (;;) {
        u32 v = __hip_atomic_load(tready + (lane & 15), __ATOMIC_RELAXED,
                                  __HIP_MEMORY_SCOPE_AGENT);
        if (__all((int)(v >= seq))) break;
        if (++it > 16384) { ok = 0; break; }
        __builtin_amdgcn_s_sleep(2);
      }
      if (!ok) break;
    }
    // publish own 64B slot + stamp with the candidate flavor (steady-state-exact)
    if (lane < 8) {
      u64 v = 0x9E3779B97F4A7C15ull * (u64)(seq * 131u + (u32)mem * 17u + (u32)lane + 1u);
      st_u64_flav(td + mem * 8 + lane, v, sc0flav);
    }
    asm volatile("s_waitcnt vmcnt(0)" ::: "memory");
    if (lane == 0) st_u32_flav(tstamp + mem * 16, seq, sc0flav);
    // detect via sc0 polls (small cap: working pipe detects in <10 iters)
    int saw = 0;
    {
      int it = 0;
      for (;;) {
        u32 s = ld_u32_sc0(tstamp + (lane & 15) * 16);
        if (__all((int)(s >= seq))) { saw = 1; break; }
        if (++it > 256) break;
        __builtin_amdgcn_s_sleep(2);
      }
    }
    if (!saw) { ok = 0; continue; }   // stay in lockstep for round 2 handshake
    // verify all 16 slots via sc0 loads
    {
      u64 a, b;
      asm volatile("global_load_dwordx2 %0, %2, off sc0\n\t"
                   "global_load_dwordx2 %1, %3, off sc0\n\t"
                   "s_waitcnt vmcnt(0)"
                   : "=v"(a), "=v"(b)
                   : "v"(td + lane), "v"(td + lane + 64) : "memory");
      int s0 = lane >> 3, j0 = lane & 7;
      int s1 = (lane + 64) >> 3, j1 = (lane + 64) & 7;
      u64 e0 = 0x9E3779B97F4A7C15ull * (u64)(seq * 131u + (u32)s0 * 17u + (u32)j0 + 1u);
      u64 e1 = 0x9E3779B97F4A7C15ull * (u64)(seq * 131u + (u32)s1 * 17u + (u32)j1 + 1u);
      if (!__all((int)((a == e0) && (b == e1)))) ok = 0;
    }
  }
  return ok;
}
// aggregate a combo verdict group-wide (agent path; member 0 decides)
__device__ int combo_verdict(u32* tverd, u32* tdec, int mem, int lane, int ok) {
  if (lane == 0)
    __hip_atomic_store(tverd + mem, ok ? 2u : 1u, __ATOMIC_RELEASE, __HIP_MEMORY_SCOPE_AGENT);
  if (mem == 0) {
    u32 dec = 2; int it = 0;
    for (;;) {
      u32 vv = (lane < 16)
        ? __hip_atomic_load(tverd + lane, __ATOMIC_RELAXED, __HIP_MEMORY_SCOPE_AGENT) : 2u;
      if (__all((int)(vv != 0u))) { if (!__all((int)(vv == 2u))) dec = 1; break; }
      if (++it > 32768) { dec = 1; break; }
      __builtin_amdgcn_s_sleep(2);
    }
    if (lane == 0)
      __hip_atomic_store(tdec, dec, __ATOMIC_RELEASE, __HIP_MEMORY_SCOPE_AGENT);
  }
  u32 d;
  for (;;) {   // member 0 always publishes; converges
    d = __hip_atomic_load(tdec, __ATOMIC_RELAXED, __HIP_MEMORY_SCOPE_AGENT);
    if (d) break;
    __builtin_amdgcn_s_sleep(2);
  }
  return d == 2u;
}

// ---- weight conversion: blob[mem][mat][col][k] bf16, k contiguous ----
__global__ void conv_weights(
    const float* __restrict__ wf, const float* __restrict__ wi,
    const float* __restrict__ wc, const float* __restrict__ wo,
    const float* __restrict__ rf, const float* __restrict__ ri,
    const float* __restrict__ rc, const float* __restrict__ ro,
    const float* __restrict__ pf, const float* __restrict__ pi,
    const float* __restrict__ po, ushort_t* __restrict__ blob)
{
  int id = blockIdx.x * 256 + threadIdx.x;   // 720896 total, exact
  int k   = id & 255;
  int col = (id >> 8) & 15;
  int q   = id >> 12;          // 0..175
  int m   = q % 11;
  int mm  = q / 11;
  const float* srcs[11] = {wf, wi, wc, wo, rf, ri, rc, ro, pf, pi, po};
  float v = srcs[m][k * 256 + mm * 16 + col];
  unsigned u = __float_as_uint(v);
  blob[id] = (ushort_t)((u + 0x7fffu + ((u >> 16) & 1u)) >> 16);
}

// ---- persistent recurrent kernel ----
extern "C" __global__ void __launch_bounds__(128, 1)
lstm_rec(const float* __restrict__ x, const ushort_t* __restrict__ blob,
         ushort_t* __restrict__ h_ex, ushort_t* __restrict__ c_ex,
         u32* __restrict__ stamps, u32* __restrict__ tst,
         const float* __restrict__ bfv, const float* __restrict__ biv,
         const float* __restrict__ bcv, const float* __restrict__ bov,
         float* __restrict__ out)
{
  __shared__ ushort_t xa[16 * 264];     // x(t) bf16, row stride 264
  __shared__ float pre[4][16][17];      // gate preacts
  __shared__ float pop[16][17];         // po partial (wave1)
  __shared__ float cn_f32[16][16];      // own-col c state, f32
  __shared__ ushort_t cn_bf[16][16];
  __shared__ ushort_t hn_bf[16][16];
  __shared__ float bia[4][16];
  __shared__ int s_mode;

  const int tid = threadIdx.x;
  const int bid = blockIdx.x;
  const int grp = bid & 7;
  const int mem = bid >> 3;
  const int gb0 = grp * 16;
  const int gc0 = mem * 16;

  const int wv = tid >> 6;
  const int lane = tid & 63;
  const int lr = lane & 15;
  const int lk = lane >> 4;

  // ---- weight fragments -> registers ----
  const ushort_t* wb = blob + (size_t)mem * CHUNK_ELEMS;
  short8 wXa[8], wXb[8], wRa[8], wRb[8], wPa[8], wPb[8];
  {
    const int m0 = wv ? 2 : 0;
    const int p0 = wv ? 10 : 8;
    const int p1 = wv ? 10 : 9;
#pragma unroll
    for (int s = 0; s < 8; ++s) {
      const int ko = s * 32 + lk * 8;
      wXa[s] = *(const short8*)(wb + ((m0    ) * 16 + lr) * 256 + ko);
      wXb[s] = *(const short8*)(wb + ((m0 + 1) * 16 + lr) * 256 + ko);
      wRa[s] = *(const short8*)(wb + ((m0 + 4) * 16 + lr) * 256 + ko);
      wRb[s] = *(const short8*)(wb + ((m0 + 5) * 16 + lr) * 256 + ko);
      wPa[s] = *(const short8*)(wb + (p0 * 16 + lr) * 256 + ko);
      wPb[s] = *(const short8*)(wb + (p1 * 16 + lr) * 256 + ko);
    }
  }

  if (tid < 64) {
    const float* bs = (tid < 16) ? bfv : (tid < 32) ? biv : (tid < 48) ? bcv : bov;
    bia[tid >> 4][tid & 15] = bs[gc0 + (tid & 15)];
  }
  const int pb = tid >> 3, pc = (tid & 7) * 2;
  cn_f32[pb][pc] = 0.f;
  cn_f32[pb][pc + 1] = 0.f;

  // stage x(0) -> xa (bf16)
  const int xr = tid >> 3, xc = (tid & 7) * 32;
  {
    const float* xp = x + (size_t)(gb0 + xr) * TT * DU + xc;
#pragma unroll
    for (int u = 0; u < 8; ++u) {
      float4 f = *(const float4*)(xp + u * 4);
      u64 pk = (u64)f2bf(f.x) | ((u64)f2bf(f.y) << 16) |
               ((u64)f2bf(f.z) << 32) | ((u64)f2bf(f.w) << 48);
      *(u64*)&xa[xr * 264 + xc + u * 4] = pk;
    }
  }

  // ---- protocol self-test: pick fastest working exchange mode for this group ----
  if (wv == 0) {
    u32* tb = tst + grp * 1024;
    int mode = 0;
    int okA = test_combo(tb, mem, lane, 1, 1u);           // sc0 stores + sc0 loads
    if (combo_verdict(tb + 528, tb + 544, mem, lane, okA)) mode = 2;
    else {
      int okB = test_combo(tb, mem, lane, 0, 3u);         // sc1 stores + sc0 loads
      if (combo_verdict(tb + 560, tb + 576, mem, lane, okB)) mode = 1;
    }
    if (lane == 0) s_mode = mode;
  }
  __syncthreads();                         // xa ready + s_mode ready
  const int mode = s_mode;
  int wedged = 0;                          // sticky: capped fast-wait failed

  const floatx4 z4 = {0.f, 0.f, 0.f, 0.f};
  floatx4 accA = z4, accB = z4;
  // prologue: x(0)@W  (c(-1)=0 so no peephole term)
#pragma unroll
  for (int s = 0; s < 8; ++s) {
    short8 a = *(const short8*)&xa[lr * 264 + s * 32 + lk * 8];
    accA = MFMA(a, wXa[s], accA);
    accB = MFMA(a, wXb[s], accB);
  }

  u32* stG = stamps + grp * 256;          // 16 members x 16 u32 (64B line each)
  ushort_t* cG = c_ex + grp * 16 * 256;   // 16 slots x 256 ushorts (512 B)
  ushort_t* hG = h_ex + grp * 16 * 256;
  const int sb = lane >> 2, sc = (lane & 3) * 4;

  for (int t = 0; t < TT; ++t) {
    // ---- h-part: wait h(t-1), pre += h(t-1)@R ----
    if (t > 0) {
      if (mode) {
        if (!wedged && !wait_stamps(stG, 2u * (u32)t, lane, mode)) wedged = 1;
        short8 hf[8];
#pragma unroll
        for (int s = 0; s < 8; ++s) {
          int k = s * 32 + lk * 8;
          hf[s] = ldfrag_sc0_issue(hG + (k >> 4) * 256 + lr * 16 + (k & 15));
        }
        asm volatile("s_waitcnt vmcnt(0)" ::: "memory");
        __builtin_amdgcn_sched_barrier(0);
#pragma unroll
        for (int s = 0; s < 8; ++s) {
          accA = MFMA(hf[s], wRa[s], accA);
          accB = MFMA(hf[s], wRb[s], accB);
        }
      } else {
        wait_stamps(stG, 2u * (u32)t, lane, 0);
#pragma unroll
        for (int s = 0; s < 8; ++s) {
          int k = s * 32 + lk * 8;
          short8 hf = ldfrag(hG + (k >> 4) * 256 + lr * 16 + (k & 15));
          accA = MFMA(hf, wRa[s], accA);
          accB = MFMA(hf, wRb[s], accB);
        }
      }
    }
#pragma unroll
    for (int r = 0; r < 4; ++r) {
      pre[wv * 2    ][lk * 4 + r][lr] = accA[r];
      pre[wv * 2 + 1][lk * 4 + r][lr] = accB[r];
    }
    __syncthreads();                                  // S1: pre complete

    // ---- pointwise 1: f,i,c~ -> c_new ----
#pragma unroll
    for (int e = 0; e < 2; ++e) {
      int c = pc + e;
      float fg = sigf(pre[0][pb][c] + bia[0][c]);
      float ig = sigf(pre[1][pb][c] + bia[1][c]);
      float ct = tanhf_(pre[2][pb][c] + bia[2][c]);
      float cn = fg * cn_f32[pb][c] + ig * ct;
      cn_f32[pb][c] = cn;
      cn_bf[pb][c] = f2bf(cn);
    }
    __syncthreads();                                  // S2: cn_bf complete

    // ---- publish c ----
    if (wv == 0) {
      u64 v = *(const u64*)&cn_bf[sb][sc];
      publish(cG + mem * 256 + sb * 16 + sc, v, stG + mem * 16,
              2u * (u32)t + 1u, lane == 0, mode);
    }

    // ---- x(t+1) HBM prefetch fills the c-wait window ----
    float4 xf[8];
    if (t < TT - 1) {
      const float* xp = x + ((size_t)(gb0 + xr) * TT + (t + 1)) * DU + xc;
#pragma unroll
      for (int u = 0; u < 8; ++u) xf[u] = *(const float4*)(xp + u * 4);
    }
    if (mode) { if (!wedged && !wait_stamps(stG, 2u * (u32)t + 1u, lane, mode)) wedged = 1; }
    else      wait_stamps(stG, 2u * (u32)t + 1u, lane, 0);   // c(t) visible

    // ---- phase B: po matvec (wave1) + next-step peepholes (wave0) ----
    {
      short8 cf[8];
      if (mode) {
#pragma unroll
        for (int s = 0; s < 8; ++s) {
          int k = s * 32 + lk * 8;
          cf[s] = ldfrag_sc0_issue(cG + (k >> 4) * 256 + lr * 16 + (k & 15));
        }
        asm volatile("s_waitcnt vmcnt(0)" ::: "memory");
        __builtin_amdgcn_sched_barrier(0);
      } else {
#pragma unroll
        for (int s = 0; s < 8; ++s) {
          int k = s * 32 + lk * 8;
          cf[s] = ldfrag(cG + (k >> 4) * 256 + lr * 16 + (k & 15));
        }
      }
      if (wv == 0) {
        accA = z4; accB = z4;                          // start step-t+1 accumulators
#pragma unroll
        for (int s = 0; s < 8; ++s) {
          accA = MFMA(cf[s], wPa[s], accA);            // c(t)@pf
          accB = MFMA(cf[s], wPb[s], accB);            // c(t)@pi
        }
      } else {
        floatx4 pacc = z4;
#pragma unroll
        for (int s = 0; s < 8; ++s)
          pacc = MFMA(cf[s], wPa[s], pacc);            // c(t)@po
#pragma unroll
        for (int r = 0; r < 4; ++r) pop[lk * 4 + r][lr] = pacc[r];
      }
    }
    __syncthreads();                                  // S5: pop complete

    // ---- pointwise 2: o gate, h_new ----
#pragma unroll
    for (int e = 0; e < 2; ++e) {
      int c = pc + e;
      float og = sigf(pre[3][pb][c] + pop[pb][c] + bia[3][c]);
      float hv = tanhf_(cn_f32[pb][c]) * og;
      hn_bf[pb][c] = f2bf(hv);
      if (t == TT - 1) out[(gb0 + pb) * 256 + gc0 + c] = hv;
    }
    if (t == TT - 1) break;
    __syncthreads();                                  // S6: hn_bf complete

    // ---- publish h ----
    if (wv == 0) {
      u64 v = *(const u64*)&hn_bf[sb][sc];
      publish(hG + mem * 256 + sb * 16 + sc, v, stG + mem * 16,
              2u * (u32)t + 2u, lane == 0, mode);
    }

    // ---- stage x(t+1) into LDS, then x@W fills the h-wait window ----
#pragma unroll
    for (int u = 0; u < 8; ++u) {
      float4 f = xf[u];
      u64 pk = (u64)f2bf(f.x) | ((u64)f2bf(f.y) << 16) |
               ((u64)f2bf(f.z) << 32) | ((u64)f2bf(f.w) << 48);
      *(u64*)&xa[xr * 264 + xc + u * 4] = pk;
    }
    __syncthreads();                                  // S8: xa ready

    if (wv == 1) { accA = z4; accB = z4; }            // c~,o restart
#pragma unroll
    for (int s = 0; s < 8; ++s) {
      short8 a = *(const short8*)&xa[lr * 264 + s * 32 + lk * 8];
      accA = MFMA(a, wXa[s], accA);
      accB = MFMA(a, wXb[s], accB);
    }
    // loop head waits h-stamps (2t+2) before using h frags
  }
}

extern "C" void kernel_launch(void* const* d_in, const int* in_sizes, int n_in,
                              void* d_out, int out_size, void* d_ws, size_t ws_size,
                              hipStream_t stream) {
  const float* x   = (const float*)d_in[0];
  const float* bfv = (const float*)d_in[12];
  const float* biv = (const float*)d_in[13];
  const float* bcv = (const float*)d_in[14];
  const float* bov = (const float*)d_in[15];
  float* outp = (float*)d_out;

  char* ws = (char*)d_ws;
  ushort_t* c_exp = (ushort_t*)(ws + CEX_OFF);
  ushort_t* h_exp = (ushort_t*)(ws + HEX_OFF);
  u32* stmp = (u32*)(ws + STMP_OFF);
  u32* tstp = (u32*)(ws + TST_OFF);
  ushort_t* blob = (ushort_t*)(ws + BLOB_OFF);

  // zero exchange buffers + stamps + test region (must restart at 0 every replay)
  hipMemsetAsync(d_ws, 0, BLOB_OFF, stream);

  hipLaunchKernelGGL(conv_weights, dim3(2816), dim3(256), 0, stream,
                     (const float*)d_in[1], (const float*)d_in[2],
                     (const float*)d_in[3], (const float*)d_in[4],
                     (const float*)d_in[5], (const float*)d_in[6],
                     (const float*)d_in[7], (const float*)d_in[8],
                     (const float*)d_in[9], (const float*)d_in[10],
                     (const float*)d_in[11], blob);

  hipLaunchKernelGGL(lstm_rec, dim3(128), dim3(128), 0, stream,
                     x, (const ushort_t*)blob, h_exp, c_exp, stmp, tstp,
                     bfv, biv, bcv, bov, outp);
}